// Round 16
// baseline (323.152 us; speedup 1.0000x reference)
//
#include <hip/hip_runtime.h>
#include <math.h>

typedef short short8 __attribute__((ext_vector_type(8)));
typedef float f32x4 __attribute__((ext_vector_type(4)));
typedef unsigned short us4 __attribute__((ext_vector_type(4)));
typedef unsigned int u32x4 __attribute__((ext_vector_type(4)));
typedef unsigned short u16;
typedef unsigned int u32;

#define GAS __attribute__((address_space(1)))
#define LAS __attribute__((address_space(3)))

static __device__ __forceinline__ u16 f2bf(float f) {
    union { float f; u32 u; } v; v.f = f;
    u32 r = v.u + 0x7FFFu + ((v.u >> 16) & 1u);
    return (u16)(r >> 16);
}

static __device__ __forceinline__ u32 pk2(float a, float b) {
    return (u32)f2bf(a) | ((u32)f2bf(b) << 16);
}

static __device__ __forceinline__ u32 cvtpk(float lo, float hi) {
    u32 r;
    asm("v_cvt_pk_bf16_f32 %0, %1, %2" : "=v"(r) : "v"(lo), "v"(hi));
    return r;
}

static __device__ __forceinline__ float bf2f(u16 h) {
    union { u32 u; float f; } v; v.u = ((u32)h) << 16;
    return v.f;
}

static __device__ __forceinline__ float ftanh(float v) {
    float t = __expf(-2.0f * fabsf(v));
    float r = (1.0f - t) / (1.0f + t);
    return copysignf(r, v);
}

static __device__ __forceinline__ void gll16(const void* g, void* l) {
    __builtin_amdgcn_global_load_lds((const GAS void*)g, (LAS void*)l, 16, 0, 0);
}

// ---------- convert x rows to bf16 + row inverse norms; blocks >=16384 convert W1 ----------
__global__ __launch_bounds__(256) void k_cvt_x(const float* __restrict__ x,
                                               u16* __restrict__ xb,
                                               float* __restrict__ xinv,
                                               const float* __restrict__ W1,
                                               u16* __restrict__ w1b) {
    const int bid = blockIdx.x, t = threadIdx.x;
    if (bid >= 16384) {
        const size_t i = (size_t)(bid - 16384) * 256 + t;
        const f32x4 v = *(const f32x4*)(W1 + 4 * i);
        u32* dst = (u32*)(w1b + 4 * i);
        dst[0] = pk2(v.x, v.y); dst[1] = pk2(v.z, v.w);
        return;
    }
    const int row = bid;
    const f32x4 v = *(const f32x4*)(x + (size_t)row * 1024 + 4 * t);
    u32* dst = (u32*)(xb + (size_t)row * 1024 + 4 * t);
    dst[0] = pk2(v.x, v.y); dst[1] = pk2(v.z, v.w);
    float s = v.x * v.x + v.y * v.y + v.z * v.z + v.w * v.w;
#pragma unroll
    for (int off = 1; off < 64; off <<= 1) s += __shfl_xor(s, off, 64);
    __shared__ float red[4];
    if ((t & 63) == 0) red[t >> 6] = s;
    __syncthreads();
    if (t == 0)
        xinv[row] = 1.0f / fmaxf(sqrtf(red[0] + red[1] + red[2] + red[3]), 1e-12f);
}

// ================= shared machinery =================
#define MFMA16(a, b, c) __builtin_amdgcn_mfma_f32_16x16x32_bf16(a, b, c, 0, 0, 0)
#define SBAR() __builtin_amdgcn_s_barrier()
#define SCHED0() __builtin_amdgcn_sched_barrier(0)
#define VMW0 asm volatile("s_waitcnt vmcnt(0)" ::: "memory")
#define VMW8L asm volatile("s_waitcnt vmcnt(8) lgkmcnt(0)" ::: "memory")
#define VMW0L asm volatile("s_waitcnt vmcnt(0) lgkmcnt(0)" ::: "memory")
#define VMNOP do {} while (0)

// -------- GEMM1 tile: WAVE-SLIP, 1 barrier/tile (all bf16 via gll16) --------
// Within tile T: reads hit buf[cur] only; all 8 gll16 target buf[cur^1] -> no
// intra-tile hazard, waves drift. Tile-end vmcnt(0) retires the 8 loads
// (issued a full tile earlier; W1 L2-resident); barrier.
#define GT1S(ISS, KNX, WEND)                                                  \
  do {                                                                        \
    short8 Af[4][2], Bf0[2][2], Bf1[2][2];                                    \
    if (ISS) {                                                                \
      gll16(AG + (saO00 + (KNX)), danext + ldst);                             \
      gll16(AG + (saO01 + (KNX)), danext + 4096 + ldst);                      \
      gll16(AG + (saO10 + (KNX)), danext + 8192 + ldst);                      \
      gll16(AG + (saO11 + (KNX)), danext + 8192 + 4096 + ldst);               \
      gll16(BG + (sbO00 + (KNX)), dbnext + ldst);                             \
      gll16(BG + (sbO01 + (KNX)), dbnext + 4096 + ldst);                      \
      gll16(BG + (sbO10 + (KNX)), dbnext + 8192 + ldst);                      \
      gll16(BG + (sbO11 + (KNX)), dbnext + 8192 + 4096 + ldst);               \
    }                                                                         \
    _Pragma("unroll") for (int m = 0; m < 4; ++m) {                           \
      Af[m][0] = *(const short8*)(la + rpA[m] + sw0);                         \
      Af[m][1] = *(const short8*)(la + rpA[m] + sw1);                         \
    }                                                                         \
    _Pragma("unroll") for (int n = 0; n < 2; ++n) {                           \
      Bf0[n][0] = *(const short8*)(lb + rpB[n] + sw0);                        \
      Bf0[n][1] = *(const short8*)(lb + rpB[n] + sw1);                        \
      Bf1[n][0] = *(const short8*)(lb + rpB[n + 2] + sw0);                    \
      Bf1[n][1] = *(const short8*)(lb + rpB[n + 2] + sw1);                    \
    }                                                                         \
    __builtin_amdgcn_s_setprio(1);                                            \
    _Pragma("unroll") for (int k = 0; k < 2; ++k)                             \
      _Pragma("unroll") for (int m = 0; m < 4; ++m)                           \
        _Pragma("unroll") for (int n = 0; n < 2; ++n)                         \
          acc[m][n] = MFMA16(Af[m][k], Bf0[n][k], acc[m][n]);                 \
    _Pragma("unroll") for (int k = 0; k < 2; ++k)                             \
      _Pragma("unroll") for (int m = 0; m < 4; ++m)                           \
        _Pragma("unroll") for (int n = 0; n < 2; ++n)                         \
          acc[m][n + 2] = MFMA16(Af[m][k], Bf1[n][k], acc[m][n + 2]);         \
    __builtin_amdgcn_s_setprio(0);                                            \
    _Pragma("unroll") for (int m = 0; m < 4; ++m) {                           \
      Af[m][0] = *(const short8*)(la + rpA[m + 4] + sw0);                     \
      Af[m][1] = *(const short8*)(la + rpA[m + 4] + sw1);                     \
    }                                                                         \
    __builtin_amdgcn_s_setprio(1);                                            \
    _Pragma("unroll") for (int k = 0; k < 2; ++k)                             \
      _Pragma("unroll") for (int m = 0; m < 4; ++m)                           \
        _Pragma("unroll") for (int n = 0; n < 2; ++n)                         \
          acc[m + 4][n] = MFMA16(Af[m][k], Bf0[n][k], acc[m + 4][n]);         \
    _Pragma("unroll") for (int k = 0; k < 2; ++k)                             \
      _Pragma("unroll") for (int m = 0; m < 4; ++m)                           \
        _Pragma("unroll") for (int n = 0; n < 2; ++n)                         \
          acc[m + 4][n + 2] = MFMA16(Af[m][k], Bf1[n][k], acc[m + 4][n + 2]); \
    __builtin_amdgcn_s_setprio(0);                                            \
    SCHED0(); WEND; SBAR();                                                   \
  } while (0)

// -------- GEMM2 tile: WAVE-SLIP, 1 barrier/tile (R15, measured) --------
#define GT3(ISSA, ISSC, ISSB, KNXA, KNXB, WEND)                               \
  do {                                                                        \
    short8 Af[4][2], Bf0[2][2], Bf1[2][2];                                    \
    if (ISSA) {                                                               \
      gll16(AG + (saO00 + (KNXA)), danext + ldst);                            \
      gll16(AG + (saO01 + (KNXA)), danext + 4096 + ldst);                     \
      gll16(AG + (saO10 + (KNXA)), danext + 8192 + ldst);                     \
      gll16(AG + (saO11 + (KNXA)), danext + 8192 + 4096 + ldst);              \
    }                                                                         \
    _Pragma("unroll") for (int m = 0; m < 4; ++m) {                           \
      Af[m][0] = *(const short8*)(la + rpA[m] + sw0);                         \
      Af[m][1] = *(const short8*)(la + rpA[m] + sw1);                         \
    }                                                                         \
    _Pragma("unroll") for (int n = 0; n < 2; ++n) {                           \
      Bf0[n][0] = *(const short8*)(lb + rpB[n] + sw0);                        \
      Bf0[n][1] = *(const short8*)(lb + rpB[n] + sw1);                        \
      Bf1[n][0] = *(const short8*)(lb + rpB[n + 2] + sw0);                    \
      Bf1[n][1] = *(const short8*)(lb + rpB[n + 2] + sw1);                    \
    }                                                                         \
    __builtin_amdgcn_s_setprio(1);                                            \
    _Pragma("unroll") for (int k = 0; k < 2; ++k)                             \
      _Pragma("unroll") for (int m = 0; m < 4; ++m)                           \
        _Pragma("unroll") for (int n = 0; n < 2; ++n)                         \
          acc[m][n] = MFMA16(Af[m][k], Bf0[n][k], acc[m][n]);                 \
    _Pragma("unroll") for (int k = 0; k < 2; ++k)                             \
      _Pragma("unroll") for (int m = 0; m < 4; ++m)                           \
        _Pragma("unroll") for (int n = 0; n < 2; ++n)                         \
          acc[m][n + 2] = MFMA16(Af[m][k], Bf1[n][k], acc[m][n + 2]);         \
    __builtin_amdgcn_s_setprio(0);                                            \
    _Pragma("unroll") for (int m = 0; m < 4; ++m) {                           \
      Af[m][0] = *(const short8*)(la + rpA[m + 4] + sw0);                     \
      Af[m][1] = *(const short8*)(la + rpA[m + 4] + sw1);                     \
    }                                                                         \
    __builtin_amdgcn_s_setprio(1);                                            \
    _Pragma("unroll") for (int k = 0; k < 2; ++k)                             \
      _Pragma("unroll") for (int m = 0; m < 4; ++m)                           \
        _Pragma("unroll") for (int n = 0; n < 2; ++n)                         \
          acc[m + 4][n] = MFMA16(Af[m][k], Bf0[n][k], acc[m + 4][n]);         \
    __builtin_amdgcn_s_setprio(0);                                            \
    if (ISSC) {                                                               \
      _Pragma("unroll") for (int c = 0; c < 2; ++c) {                         \
        u32x4 wv;                                                             \
        wv.x = cvtpk(bn[2 * c].x, bn[2 * c].y);                               \
        wv.y = cvtpk(bn[2 * c].z, bn[2 * c].w);                               \
        wv.z = cvtpk(bn[2 * c + 1].x, bn[2 * c + 1].y);                       \
        wv.w = cvtpk(bn[2 * c + 1].z, bn[2 * c + 1].w);                       \
        *(u32x4*)(dbnext + c * 4096 + (tid << 3)) = wv;                       \
        if (ISSB) {                                                           \
          bn[2 * c]     = *(const f32x4*)(BGf + bro[c] + (KNXB) + swsrc);     \
          bn[2 * c + 1] = *(const f32x4*)(BGf + bro[c] + (KNXB) + swsrc + 4); \
        }                                                                     \
      }                                                                       \
    }                                                                         \
    __builtin_amdgcn_s_setprio(1);                                            \
    _Pragma("unroll") for (int k = 0; k < 2; ++k)                             \
      _Pragma("unroll") for (int m = 0; m < 4; ++m)                           \
        _Pragma("unroll") for (int n = 0; n < 2; ++n)                         \
          acc[m + 4][n + 2] = MFMA16(Af[m][k], Bf1[n][k], acc[m + 4][n + 2]); \
    __builtin_amdgcn_s_setprio(0);                                            \
    if (ISSC) {                                                               \
      _Pragma("unroll") for (int c = 2; c < 4; ++c) {                         \
        u32x4 wv;                                                             \
        wv.x = cvtpk(bn[2 * c].x, bn[2 * c].y);                               \
        wv.y = cvtpk(bn[2 * c].z, bn[2 * c].w);                               \
        wv.z = cvtpk(bn[2 * c + 1].x, bn[2 * c + 1].y);                       \
        wv.w = cvtpk(bn[2 * c + 1].z, bn[2 * c + 1].w);                       \
        *(u32x4*)(dbnext + c * 4096 + (tid << 3)) = wv;                       \
        if (ISSB) {                                                           \
          bn[2 * c]     = *(const f32x4*)(BGf + bro[c] + (KNXB) + swsrc);     \
          bn[2 * c + 1] = *(const f32x4*)(BGf + bro[c] + (KNXB) + swsrc + 4); \
        }                                                                     \
      }                                                                       \
    }                                                                         \
    SCHED0(); WEND; SBAR();                                                   \
  } while (0)

// ================= GEMM1: wg = x_bf @ W1_bf^T + b1 (wave-slip) =================
__global__ __launch_bounds__(512, 2) void k_gemm1_8ph(const u16* __restrict__ AG,
                                                      const u16* __restrict__ BG,
                                                      const float* __restrict__ bias,
                                                      u16* __restrict__ C,
                                                      float* __restrict__ wgn2) {
    __shared__ __align__(16) u16 LsA[2][16384];
    __shared__ __align__(16) u16 LsB[2][16384];
    const int K = 1024, NT = 16;
    const int lin = blockIdx.x;
    const int w = (lin & 7) * 32 + (lin >> 3);
    const int n0 = (w & 3) * 256;
    const int m0 = (w >> 2) * 256;

    const int tid = threadIdx.x, wave = tid >> 6, lane = tid & 63;
    const int lr = lane & 15, kq = lane >> 4;
    const int wr = wave >> 2, wc = wave & 3;

    const int trow = tid >> 3;
    const u32 swsrc = (u32)(((tid & 7) ^ (trow & 7)) * 8);
    const u32 saO00 = (u32)(m0 + 0 + trow) * (u32)K + swsrc;
    const u32 saO01 = (u32)(m0 + 128 + trow) * (u32)K + swsrc;
    const u32 saO10 = (u32)(m0 + 64 + trow) * (u32)K + swsrc;
    const u32 saO11 = (u32)(m0 + 192 + trow) * (u32)K + swsrc;
    const int q0 = trow, q1 = 64 + trow;
    const u32 sbO00 = (u32)(n0 + (q0 >> 5) * 64 + (q0 & 31)) * (u32)K + swsrc;
    const u32 sbO01 = (u32)(n0 + (q1 >> 5) * 64 + (q1 & 31)) * (u32)K + swsrc;
    const u32 sbO10 = (u32)(n0 + (q0 >> 5) * 64 + 32 + (q0 & 31)) * (u32)K + swsrc;
    const u32 sbO11 = (u32)(n0 + (q1 >> 5) * 64 + 32 + (q1 & 31)) * (u32)K + swsrc;
    const u32 ldst = (u32)wave * 512;

    int rpA[8], rpB[4];
#pragma unroll
    for (int mf = 0; mf < 8; ++mf)
        rpA[mf] = ((mf >> 2) * 128 + wr * 64 + (mf & 3) * 16 + lr) << 6;
#pragma unroll
    for (int nf = 0; nf < 4; ++nf)
        rpB[nf] = ((nf >> 1) * 128 + wc * 32 + (nf & 1) * 16 + lr) << 6;
    const int sw0 = ((0 + kq) ^ (lr & 7)) * 8;
    const int sw1 = ((4 + kq) ^ (lr & 7)) * 8;

    f32x4 acc[8][4] = {};

    // prologue: tile0 full
    gll16(AG + saO00, &LsA[0][0] + ldst);
    gll16(AG + saO01, &LsA[0][0] + 4096 + ldst);
    gll16(AG + saO10, &LsA[0][0] + 8192 + ldst);
    gll16(AG + saO11, &LsA[0][0] + 8192 + 4096 + ldst);
    gll16(BG + sbO00, &LsB[0][0] + ldst);
    gll16(BG + sbO01, &LsB[0][0] + 4096 + ldst);
    gll16(BG + sbO10, &LsB[0][0] + 8192 + ldst);
    gll16(BG + sbO11, &LsB[0][0] + 8192 + 4096 + ldst);
    VMW0;
    SBAR();

    int cur = 0;
    for (int T = 0; T < NT - 1; ++T) {
        const u16* la = &LsA[cur][0];
        const u16* lb = &LsB[cur][0];
        u16* danext = &LsA[cur ^ 1][0];
        u16* dbnext = &LsB[cur ^ 1][0];
        const u32 knx = (u32)(T + 1) * 64;
        GT1S(1, knx, VMW0);
        cur ^= 1;
    }
    {
        const u16* la = &LsA[cur][0];
        const u16* lb = &LsB[cur][0];
        u16* danext = &LsA[cur ^ 1][0];
        u16* dbnext = &LsB[cur ^ 1][0];
        (void)danext; (void)dbnext;
        GT1S(0, 0u, VMNOP);
    }

    const int col0 = n0 + wc * 64;
    const int row0 = m0 + wr * 128;
    float bcol[4];
#pragma unroll
    for (int nf = 0; nf < 4; ++nf) bcol[nf] = bias[col0 + nf * 16 + lr];
#pragma unroll
    for (int mf = 0; mf < 8; ++mf) {
#pragma unroll
        for (int r = 0; r < 4; ++r) {
            const int row = row0 + mf * 16 + kq * 4 + r;
            float nrm = 0.f;
#pragma unroll
            for (int nf = 0; nf < 4; ++nf) {
                float v = acc[mf][nf][r] + bcol[nf];
                C[(size_t)row * 1024 + col0 + nf * 16 + lr] = f2bf(v);
                nrm += v * v;
            }
#pragma unroll
            for (int off = 1; off < 16; off <<= 1) nrm += __shfl_xor(nrm, off, 64);
            if (lr == 0) atomicAdd(&wgn2[row], nrm);
        }
    }
}

// ================= GEMM2: part[z] = attn_bf @ W_mlp^T (wave-slip, fused cvt) ====
__global__ __launch_bounds__(512, 2) void k_gemm2_8ph(const u16* __restrict__ AG,
                                                      const float* __restrict__ BGf,
                                                      u16* __restrict__ part) {
    __shared__ __align__(16) u16 LsA[2][16384];
    __shared__ __align__(16) u16 LsB[2][16384];
    const int K = 16384, NT = 64;
    const int lin = blockIdx.x;
    const int w = (lin & 7) * 32 + (lin >> 3);
    const int m0 = (w & 3) * 256;
    const int z = (w >> 2) & 3;
    const int n0 = (w >> 4) * 256;
    const int kbeg = z * 4096;

    const int tid = threadIdx.x, wave = tid >> 6, lane = tid & 63;
    const int lr = lane & 15, kq = lane >> 4;
    const int wr = wave >> 2, wc = wave & 3;

    const int trow = tid >> 3;
    const u32 swsrc = (u32)(((tid & 7) ^ (trow & 7)) * 8);
    const u32 saO00 = (u32)(m0 + 0 + trow) * (u32)K + (u32)kbeg + swsrc;
    const u32 saO01 = (u32)(m0 + 128 + trow) * (u32)K + (u32)kbeg + swsrc;
    const u32 saO10 = (u32)(m0 + 64 + trow) * (u32)K + (u32)kbeg + swsrc;
    const u32 saO11 = (u32)(m0 + 192 + trow) * (u32)K + (u32)kbeg + swsrc;
    const int q0 = trow, q1 = 64 + trow;
    u32 bro[4];
    bro[0] = (u32)(n0 + (q0 >> 5) * 64 + (q0 & 31)) * 16384u + (u32)kbeg;
    bro[1] = (u32)(n0 + (q1 >> 5) * 64 + (q1 & 31)) * 16384u + (u32)kbeg;
    bro[2] = bro[0] + 32u * 16384u;
    bro[3] = bro[1] + 32u * 16384u;
    const u32 ldst = (u32)wave * 512;

    int rpA[8], rpB[4];
#pragma unroll
    for (int mf = 0; mf < 8; ++mf)
        rpA[mf] = ((mf >> 2) * 128 + wr * 64 + (mf & 3) * 16 + lr) << 6;
#pragma unroll
    for (int nf = 0; nf < 4; ++nf)
        rpB[nf] = ((nf >> 1) * 128 + wc * 32 + (nf & 1) * 16 + lr) << 6;
    const int sw0 = ((0 + kq) ^ (lr & 7)) * 8;
    const int sw1 = ((4 + kq) ^ (lr & 7)) * 8;

    f32x4 acc[8][4] = {};
    f32x4 bn[8];

    // prologue: tile0 (A gll16, bn f32 load + cvt -> LsB[0]); preload bn(T1)
    {
        gll16(AG + saO00, &LsA[0][0] + ldst);
        gll16(AG + saO01, &LsA[0][0] + 4096 + ldst);
        gll16(AG + saO10, &LsA[0][0] + 8192 + ldst);
        gll16(AG + saO11, &LsA[0][0] + 8192 + 4096 + ldst);
#pragma unroll
        for (int c = 0; c < 4; ++c) {
            bn[2 * c]     = *(const f32x4*)(BGf + bro[c] + swsrc);
            bn[2 * c + 1] = *(const f32x4*)(BGf + bro[c] + swsrc + 4);
        }
#pragma unroll
        for (int c = 0; c < 4; ++c) {
            u32x4 wv;
            wv.x = cvtpk(bn[2 * c].x, bn[2 * c].y);
            wv.y = cvtpk(bn[2 * c].z, bn[2 * c].w);
            wv.z = cvtpk(bn[2 * c + 1].x, bn[2 * c + 1].y);
            wv.w = cvtpk(bn[2 * c + 1].z, bn[2 * c + 1].w);
            *(u32x4*)(&LsB[0][0] + c * 4096 + (tid << 3)) = wv;
        }
        asm volatile("s_waitcnt vmcnt(0) lgkmcnt(0)" ::: "memory");
#pragma unroll
        for (int c = 0; c < 4; ++c) {
            bn[2 * c]     = *(const f32x4*)(BGf + bro[c] + 64 + swsrc);
            bn[2 * c + 1] = *(const f32x4*)(BGf + bro[c] + 64 + swsrc + 4);
        }
        SBAR();
    }

    int cur = 0;
    for (int T = 0; T < NT - 2; ++T) {
        const u16* la = &LsA[cur][0];
        const u16* lb = &LsB[cur][0];
        u16* danext = &LsA[cur ^ 1][0];
        u16* dbnext = &LsB[cur ^ 1][0];
        const u32 knxa = (u32)(T + 1) * 64;
        const u32 knxb = (u32)(T + 2) * 64;
        GT3(1, 1, 1, knxa, knxb, VMW8L);
        cur ^= 1;
    }
    {   // T = 62
        const u16* la = &LsA[cur][0];
        const u16* lb = &LsB[cur][0];
        u16* danext = &LsA[cur ^ 1][0];
        u16* dbnext = &LsB[cur ^ 1][0];
        GT3(1, 1, 0, 63u * 64, 0u, VMW0L);
        cur ^= 1;
    }
    {   // T = 63
        const u16* la = &LsA[cur][0];
        const u16* lb = &LsB[cur][0];
        u16* danext = &LsA[cur ^ 1][0];
        u16* dbnext = &LsB[cur ^ 1][0];
        (void)danext; (void)dbnext;
        GT3(0, 0, 0, 0u, 0u, VMNOP);
    }

    u16* po = part + (size_t)z * 4194304ull;
    const int col0 = n0 + wc * 64;
    const int row0 = m0 + wr * 128;
#pragma unroll
    for (int mf = 0; mf < 8; ++mf)
#pragma unroll
        for (int r = 0; r < 4; ++r) {
            const int row = row0 + mf * 16 + kq * 4 + r;
#pragma unroll
            for (int nf = 0; nf < 4; ++nf)
                po[(size_t)row * 4096 + col0 + nf * 16 + lr] = f2bf(acc[mf][nf][r]);
        }
}

// ---------- merged per-batch graph algebra + attention readout ----------
__global__ __launch_bounds__(256) void k_batch_attn(const u16* xb,
                                                    const u16* __restrict__ wgb,
                                                    const float* __restrict__ xinv,
                                                    const float* __restrict__ wgn2,
                                                    const float* __restrict__ matrix,
                                                    const float* __restrict__ a_param,
                                                    float* __restrict__ e2_out,
                                                    float* __restrict__ m_out,
                                                    u16* attn_bf) {
    const int b = blockIdx.x, tid = threadIdx.x;
    const int wave = tid >> 6, lane = tid & 63;
    const int j = lane & 15, ig = (lane >> 4) * 4;

    __shared__ float qred[4][64][4];
    __shared__ float esm_l[16 * 17];
    __shared__ float fi_l[16 * 17];
    __shared__ float e2_l[16 * 17];
    __shared__ float m_l[256];
    __shared__ float as_l[256];
    __shared__ u16 xsh[16][256];

    {
        const size_t roff = (size_t)(b * 16 + j) * 1024 + (lane >> 4) * 8 + wave * 256;
        f32x4 acc0 = {}, acc1 = {};
#pragma unroll
        for (int kt = 0; kt < 256; kt += 64) {
            short8 xa0 = *(const short8*)(xb + roff + kt);
            short8 wa0 = *(const short8*)(wgb + roff + kt);
            short8 xa1 = *(const short8*)(xb + roff + kt + 32);
            short8 wa1 = *(const short8*)(wgb + roff + kt + 32);
            acc0 = __builtin_amdgcn_mfma_f32_16x16x32_bf16(xa0, wa0, acc0, 0, 0, 0);
            acc1 = __builtin_amdgcn_mfma_f32_16x16x32_bf16(xa1, wa1, acc1, 0, 0, 0);
        }
#pragma unroll
        for (int r = 0; r < 4; ++r) qred[wave][lane][r] = acc0[r] + acc1[r];
    }
    __syncthreads();

    if (tid < 64) {
        const int l = tid;
        const float inw = 1.0f / fmaxf(sqrtf(wgn2[b * 16 + j]), 1e-12f);
        const float boost = 1.0f + a_param[0];
        float e[4];
#pragma unroll
        for (int r = 0; r < 4; ++r) {
            const int i = ig + r;
            float v = (qred[0][l][r] + qred[1][l][r] + qred[2][l][r] + qred[3][l][r]) *
                      xinv[b * 16 + i] * inw;
            if (i == j) v *= boost;
            e[r] = v;
            as_l[i * 16 + j] = v;
        }
        float mx = fmaxf(fmaxf(e[0], e[1]), fmaxf(e[2], e[3]));
        mx = fmaxf(mx, __shfl_xor(mx, 16, 64));
        mx = fmaxf(mx, __shfl_xor(mx, 32, 64));
        float p[4], s = 0.f;
#pragma unroll
        for (int r = 0; r < 4; ++r) { p[r] = __expf(e[r] - mx); s += p[r]; }
        s += __shfl_xor(s, 16, 64);
        s += __shfl_xor(s, 32, 64);
        const float invs = 1.0f / s;
#pragma unroll
        for (int r = 0; r < 4; ++r) esm_l[(ig + r) * 17 + j] = p[r] * invs;
        const f32x4 mv = *(const f32x4*)(matrix + (size_t)b * 256 + 4 * l);
        *(f32x4*)(m_l + 4 * l) = mv;
        *(f32x4*)(m_out + (size_t)b * 256 + 4 * l) = mv;
    }
    __syncthreads();
    if (tid < 64) {
        float fi[4] = {0, 0, 0, 0};
#pragma unroll
        for (int t = 0; t < 16; ++t) {
            const float mk = m_l[t * 16 + j];
#pragma unroll
            for (int r = 0; r < 4; ++r) fi[r] += esm_l[(ig + r) * 17 + t] * mk;
        }
#pragma unroll
        for (int r = 0; r < 4; ++r) fi_l[(ig + r) * 17 + j] = fi[r];
    }
    __syncthreads();
    if (tid < 64) {
        float e2v[4] = {0, 0, 0, 0};
#pragma unroll
        for (int kk = 0; kk < 16; ++kk) {
            const float wgt = esm_l[j * 17 + kk] * m_l[kk * 16 + kk];
#pragma unroll
            for (int r = 0; r < 4; ++r) e2v[r] += fi_l[(ig + r) * 17 + kk] * wgt;
        }
#pragma unroll
        for (int r = 0; r < 4; ++r) e2_l[(ig + r) * 17 + j] = e2v[r];
    }
    __syncthreads();
    if (tid < 64) {
#pragma unroll
        for (int r = 0; r < 4; ++r) {
            const int i = ig + r;
            e2_out[(size_t)b * 256 + i * 16 + j] =
                0.5f * (e2_l[i * 17 + j] + e2_l[j * 17 + i]);
        }
    }

    const int srow = tid >> 4;
    const int scol = (tid & 15) * 16;
    for (int ch = 0; ch < 4; ++ch) {
        __syncthreads();
        const u16* src = xb + ((size_t)b * 16 + srow) * 1024 + ch * 256 + scol;
        *(short8*)&xsh[srow][scol] = *(const short8*)src;
        *(short8*)&xsh[srow][scol + 8] = *(const short8*)(src + 8);
        __syncthreads();
        float accv[16] = {};
#pragma unroll
        for (int jj = 0; jj < 16; ++jj) {
            const float xv = bf2f(xsh[jj][tid]);
#pragma unroll
            for (int i = 0; i < 16; ++i) accv[i] = fmaf(as_l[jj * 16 + i], xv, accv[i]);
        }
#pragma unroll
        for (int i = 0; i < 16; ++i)
            attn_bf[((size_t)b * 16 + i) * 1024 + ch * 256 + tid] = f2bf(ftanh(accv[i]));
    }
}

// ---------- broadcast: out[b, rep, :] = sum_z part[z][b,:] + b_mlp ----------
__global__ __launch_bounds__(256) void k_bcast(const u16* __restrict__ p,
                                               const float* __restrict__ bias,
                                               float* __restrict__ out) {
    const size_t i = (size_t)blockIdx.x * 256 + threadIdx.x;
    const int o4 = (int)(i & 1023);
    const int b = (int)(i >> 14);
    const size_t src = (size_t)b * 4096 + (size_t)o4 * 4;
    f32x4 r = *(const f32x4*)(bias + (size_t)o4 * 4);
#pragma unroll
    for (int z = 0; z < 4; ++z) {
        us4 v = *(const us4*)(p + (size_t)z * 4194304ull + src);
        r.x += bf2f(v.x); r.y += bf2f(v.y); r.z += bf2f(v.z); r.w += bf2f(v.w);
    }
    *(f32x4*)(out + i * 4) = r;
}

extern "C" void kernel_launch(void* const* d_in, const int* in_sizes, int n_in,
                              void* d_out, int out_size, void* d_ws, size_t ws_size,
                              hipStream_t stream) {
    const float* x      = (const float*)d_in[0];
    const float* matrix = (const float*)d_in[1];
    const float* W1     = (const float*)d_in[2];
    const float* b1     = (const float*)d_in[3];
    const float* W_mlp  = (const float*)d_in[4];
    const float* b_mlp  = (const float*)d_in[5];
    const float* a_par  = (const float*)d_in[6];
    float* out = (float*)d_out;

    char* ws = (char*)d_ws;
    size_t off = 0;
    auto alloc = [&](size_t bytes) {
        char* p = ws + off;
        off += (bytes + 255) & ~(size_t)255;
        return p;
    };
    u16*   x_bf  = (u16*)alloc(16384ull * 1024 * 2);    // reused as attn_bf
    u16*   wg_bf = (u16*)alloc(16384ull * 1024 * 2);    // reused as GEMM2 bf16 partials
    u16*   w1_bf = (u16*)alloc(1024ull * 1024 * 2);
    float* xinv  = (float*)alloc(16384ull * 4);
    float* wgn2  = (float*)alloc(16384ull * 4);
    u16*   attn_bf = x_bf;
    u16*   part    = wg_bf;
    float* e2_out = out + 67108864ull;
    float* m_out  = out + 67371008ull;

    hipMemsetAsync(wgn2, 0, 16384 * 4, stream);
    k_cvt_x<<<17408, 256, 0, stream>>>(x, x_bf, xinv, W1, w1_bf);
    k_gemm1_8ph<<<256, 512, 0, stream>>>(x_bf, w1_bf, b1, wg_bf, wgn2);
    k_batch_attn<<<1024, 256, 0, stream>>>(x_bf, wg_bf, xinv, wgn2, matrix, a_par,
                                           e2_out, m_out, attn_bf);
    k_gemm2_8ph<<<256, 512, 0, stream>>>(attn_bf, W_mlp, part);
    k_bcast<<<65536, 256, 0, stream>>>(part, b_mlp, out);
}

// Round 17
// 317.703 us; speedup vs baseline: 1.0172x; 1.0172x over previous
//
#include <hip/hip_runtime.h>
#include <math.h>

typedef short short8 __attribute__((ext_vector_type(8)));
typedef float f32x4 __attribute__((ext_vector_type(4)));
typedef unsigned short us4 __attribute__((ext_vector_type(4)));
typedef unsigned int u32x4 __attribute__((ext_vector_type(4)));
typedef unsigned short u16;
typedef unsigned int u32;

#define GAS __attribute__((address_space(1)))
#define LAS __attribute__((address_space(3)))

static __device__ __forceinline__ u16 f2bf(float f) {
    union { float f; u32 u; } v; v.f = f;
    u32 r = v.u + 0x7FFFu + ((v.u >> 16) & 1u);
    return (u16)(r >> 16);
}

static __device__ __forceinline__ u32 pk2(float a, float b) {
    return (u32)f2bf(a) | ((u32)f2bf(b) << 16);
}

static __device__ __forceinline__ u32 cvtpk(float lo, float hi) {
    u32 r;
    asm("v_cvt_pk_bf16_f32 %0, %1, %2" : "=v"(r) : "v"(lo), "v"(hi));
    return r;
}

static __device__ __forceinline__ float bf2f(u16 h) {
    union { u32 u; float f; } v; v.u = ((u32)h) << 16;
    return v.f;
}

static __device__ __forceinline__ float ftanh(float v) {
    float t = __expf(-2.0f * fabsf(v));
    float r = (1.0f - t) / (1.0f + t);
    return copysignf(r, v);
}

static __device__ __forceinline__ void gll16(const void* g, void* l) {
    __builtin_amdgcn_global_load_lds((const GAS void*)g, (LAS void*)l, 16, 0, 0);
}

// ---------- convert x rows to bf16 + row inverse norms; blocks >=16384 convert W1 ----------
__global__ __launch_bounds__(256) void k_cvt_x(const float* __restrict__ x,
                                               u16* __restrict__ xb,
                                               float* __restrict__ xinv,
                                               const float* __restrict__ W1,
                                               u16* __restrict__ w1b) {
    const int bid = blockIdx.x, t = threadIdx.x;
    if (bid >= 16384) {
        const size_t i = (size_t)(bid - 16384) * 256 + t;
        const f32x4 v = *(const f32x4*)(W1 + 4 * i);
        u32* dst = (u32*)(w1b + 4 * i);
        dst[0] = pk2(v.x, v.y); dst[1] = pk2(v.z, v.w);
        return;
    }
    const int row = bid;
    const f32x4 v = *(const f32x4*)(x + (size_t)row * 1024 + 4 * t);
    u32* dst = (u32*)(xb + (size_t)row * 1024 + 4 * t);
    dst[0] = pk2(v.x, v.y); dst[1] = pk2(v.z, v.w);
    float s = v.x * v.x + v.y * v.y + v.z * v.z + v.w * v.w;
#pragma unroll
    for (int off = 1; off < 64; off <<= 1) s += __shfl_xor(s, off, 64);
    __shared__ float red[4];
    if ((t & 63) == 0) red[t >> 6] = s;
    __syncthreads();
    if (t == 0)
        xinv[row] = 1.0f / fmaxf(sqrtf(red[0] + red[1] + red[2] + red[3]), 1e-12f);
}

// ================= shared machinery =================
#define MFMA16(a, b, c) __builtin_amdgcn_mfma_f32_16x16x32_bf16(a, b, c, 0, 0, 0)
#define SBAR() __builtin_amdgcn_s_barrier()
#define SCHED0() __builtin_amdgcn_sched_barrier(0)
#define VMW6 asm volatile("s_waitcnt vmcnt(6)" ::: "memory")
#define VMW4 asm volatile("s_waitcnt vmcnt(4)" ::: "memory")
#define VMW2 asm volatile("s_waitcnt vmcnt(2)" ::: "memory")
#define VMW0 asm volatile("s_waitcnt vmcnt(0)" ::: "memory")
#define VMW8L asm volatile("s_waitcnt vmcnt(8) lgkmcnt(0)" ::: "memory")
#define VMW0L asm volatile("s_waitcnt vmcnt(0) lgkmcnt(0)" ::: "memory")
#define LGKML asm volatile("s_waitcnt lgkmcnt(0)" ::: "memory")
#define VMNOP do {} while (0)

// -------- GEMM1 tile: deep-prefetch, 2 gll16/phase, uniform vmcnt(6) --------
#define DO_T1(I0, I1, I2, I3, W0, W1M, W2, W3)                                \
  do {                                                                        \
    short8 Af[4][2], Bf0[2][2], Bf1[2][2];                                    \
    _Pragma("unroll") for (int m = 0; m < 4; ++m) {                           \
      Af[m][0] = *(const short8*)(la + rpA[m] + sw0);                         \
      Af[m][1] = *(const short8*)(la + rpA[m] + sw1);                         \
    }                                                                         \
    _Pragma("unroll") for (int n = 0; n < 2; ++n) {                           \
      Bf0[n][0] = *(const short8*)(lb + rpB[n] + sw0);                        \
      Bf0[n][1] = *(const short8*)(lb + rpB[n] + sw1);                        \
    }                                                                         \
    if (I0) { gll16(AG + (saO00 + knxa), danext + ldst);                      \
              gll16(AG + (saO01 + knxa), danext + 4096 + ldst); }             \
    SBAR(); SCHED0();                                                         \
    __builtin_amdgcn_s_setprio(1);                                            \
    _Pragma("unroll") for (int k = 0; k < 2; ++k)                             \
      _Pragma("unroll") for (int m = 0; m < 4; ++m)                           \
        _Pragma("unroll") for (int n = 0; n < 2; ++n)                         \
          acc[m][n] = MFMA16(Af[m][k], Bf0[n][k], acc[m][n]);                 \
    __builtin_amdgcn_s_setprio(0); SCHED0(); W0; SBAR();                      \
    _Pragma("unroll") for (int n = 0; n < 2; ++n) {                           \
      Bf1[n][0] = *(const short8*)(lb + rpB[n + 2] + sw0);                    \
      Bf1[n][1] = *(const short8*)(lb + rpB[n + 2] + sw1);                    \
    }                                                                         \
    if (I1) { gll16(BG + (sbO10 + knxa), dbnext + 8192 + ldst);               \
              gll16(BG + (sbO11 + knxa), dbnext + 8192 + 4096 + ldst); }      \
    SBAR(); SCHED0();                                                         \
    __builtin_amdgcn_s_setprio(1);                                            \
    _Pragma("unroll") for (int k = 0; k < 2; ++k)                             \
      _Pragma("unroll") for (int m = 0; m < 4; ++m)                           \
        _Pragma("unroll") for (int n = 0; n < 2; ++n)                         \
          acc[m][n + 2] = MFMA16(Af[m][k], Bf1[n][k], acc[m][n + 2]);         \
    __builtin_amdgcn_s_setprio(0); SCHED0(); W1M; SBAR();                     \
    _Pragma("unroll") for (int m = 0; m < 4; ++m) {                           \
      Af[m][0] = *(const short8*)(la + rpA[m + 4] + sw0);                     \
      Af[m][1] = *(const short8*)(la + rpA[m + 4] + sw1);                     \
    }                                                                         \
    if (I2) { gll16(AG + (saO10 + knxa), danext + 8192 + ldst);               \
              gll16(AG + (saO11 + knxa), danext + 8192 + 4096 + ldst); }      \
    SBAR(); SCHED0();                                                         \
    __builtin_amdgcn_s_setprio(1);                                            \
    _Pragma("unroll") for (int k = 0; k < 2; ++k)                             \
      _Pragma("unroll") for (int m = 0; m < 4; ++m)                           \
        _Pragma("unroll") for (int n = 0; n < 2; ++n)                         \
          acc[m + 4][n] = MFMA16(Af[m][k], Bf0[n][k], acc[m + 4][n]);         \
    __builtin_amdgcn_s_setprio(0); SCHED0(); W2; SBAR();                      \
    if (I3) { gll16(BG + (sbO00 + knxb), lbw + ldst);                         \
              gll16(BG + (sbO01 + knxb), lbw + 4096 + ldst); }                \
    SBAR(); SCHED0();                                                         \
    __builtin_amdgcn_s_setprio(1);                                            \
    _Pragma("unroll") for (int k = 0; k < 2; ++k)                             \
      _Pragma("unroll") for (int m = 0; m < 4; ++m)                           \
        _Pragma("unroll") for (int n = 0; n < 2; ++n)                         \
          acc[m + 4][n + 2] = MFMA16(Af[m][k], Bf1[n][k], acc[m + 4][n + 2]); \
    __builtin_amdgcn_s_setprio(0); SCHED0(); W3; SBAR();                      \
  } while (0)

#define GEMM1_PROLOGUE()                                                      \
  do {                                                                        \
    gll16(AG + saO00, &LsA[0][0] + ldst);                                     \
    gll16(AG + saO01, &LsA[0][0] + 4096 + ldst);                              \
    gll16(BG + sbO00, &LsB[0][0] + ldst);                                     \
    gll16(BG + sbO01, &LsB[0][0] + 4096 + ldst);                              \
    gll16(BG + sbO10, &LsB[0][0] + 8192 + ldst);                              \
    gll16(BG + sbO11, &LsB[0][0] + 8192 + 4096 + ldst);                       \
    gll16(AG + saO10, &LsA[0][0] + 8192 + ldst);                              \
    gll16(AG + saO11, &LsA[0][0] + 8192 + 4096 + ldst);                       \
    gll16(BG + sbO00 + 64, &LsB[1][0] + ldst);                                \
    gll16(BG + sbO01 + 64, &LsB[1][0] + 4096 + ldst);                         \
    VMW6; SBAR();                                                             \
  } while (0)

// -------- GEMM2 tile: WAVE-SLIP, 1 barrier/tile (R15, best measured) --------
#define GT3(ISSA, ISSC, ISSB, KNXA, KNXB, WEND)                               \
  do {                                                                        \
    short8 Af[4][2], Bf0[2][2], Bf1[2][2];                                    \
    if (ISSA) {                                                               \
      gll16(AG + (saO00 + (KNXA)), danext + ldst);                            \
      gll16(AG + (saO01 + (KNXA)), danext + 4096 + ldst);                     \
      gll16(AG + (saO10 + (KNXA)), danext + 8192 + ldst);                     \
      gll16(AG + (saO11 + (KNXA)), danext + 8192 + 4096 + ldst);              \
    }                                                                         \
    _Pragma("unroll") for (int m = 0; m < 4; ++m) {                           \
      Af[m][0] = *(const short8*)(la + rpA[m] + sw0);                         \
      Af[m][1] = *(const short8*)(la + rpA[m] + sw1);                         \
    }                                                                         \
    _Pragma("unroll") for (int n = 0; n < 2; ++n) {                           \
      Bf0[n][0] = *(const short8*)(lb + rpB[n] + sw0);                        \
      Bf0[n][1] = *(const short8*)(lb + rpB[n] + sw1);                        \
      Bf1[n][0] = *(const short8*)(lb + rpB[n + 2] + sw0);                    \
      Bf1[n][1] = *(const short8*)(lb + rpB[n + 2] + sw1);                    \
    }                                                                         \
    __builtin_amdgcn_s_setprio(1);                                            \
    _Pragma("unroll") for (int k = 0; k < 2; ++k)                             \
      _Pragma("unroll") for (int m = 0; m < 4; ++m)                           \
        _Pragma("unroll") for (int n = 0; n < 2; ++n)                         \
          acc[m][n] = MFMA16(Af[m][k], Bf0[n][k], acc[m][n]);                 \
    _Pragma("unroll") for (int k = 0; k < 2; ++k)                             \
      _Pragma("unroll") for (int m = 0; m < 4; ++m)                           \
        _Pragma("unroll") for (int n = 0; n < 2; ++n)                         \
          acc[m][n + 2] = MFMA16(Af[m][k], Bf1[n][k], acc[m][n + 2]);         \
    __builtin_amdgcn_s_setprio(0);                                            \
    _Pragma("unroll") for (int m = 0; m < 4; ++m) {                           \
      Af[m][0] = *(const short8*)(la + rpA[m + 4] + sw0);                     \
      Af[m][1] = *(const short8*)(la + rpA[m + 4] + sw1);                     \
    }                                                                         \
    __builtin_amdgcn_s_setprio(1);                                            \
    _Pragma("unroll") for (int k = 0; k < 2; ++k)                             \
      _Pragma("unroll") for (int m = 0; m < 4; ++m)                           \
        _Pragma("unroll") for (int n = 0; n < 2; ++n)                         \
          acc[m + 4][n] = MFMA16(Af[m][k], Bf0[n][k], acc[m + 4][n]);         \
    __builtin_amdgcn_s_setprio(0);                                            \
    if (ISSC) {                                                               \
      _Pragma("unroll") for (int c = 0; c < 2; ++c) {                         \
        u32x4 wv;                                                             \
        wv.x = cvtpk(bn[2 * c].x, bn[2 * c].y);                               \
        wv.y = cvtpk(bn[2 * c].z, bn[2 * c].w);                               \
        wv.z = cvtpk(bn[2 * c + 1].x, bn[2 * c + 1].y);                       \
        wv.w = cvtpk(bn[2 * c + 1].z, bn[2 * c + 1].w);                       \
        *(u32x4*)(dbnext + c * 4096 + (tid << 3)) = wv;                       \
        if (ISSB) {                                                           \
          bn[2 * c]     = *(const f32x4*)(BGf + bro[c] + (KNXB) + swsrc);     \
          bn[2 * c + 1] = *(const f32x4*)(BGf + bro[c] + (KNXB) + swsrc + 4); \
        }                                                                     \
      }                                                                       \
    }                                                                         \
    __builtin_amdgcn_s_setprio(1);                                            \
    _Pragma("unroll") for (int k = 0; k < 2; ++k)                             \
      _Pragma("unroll") for (int m = 0; m < 4; ++m)                           \
        _Pragma("unroll") for (int n = 0; n < 2; ++n)                         \
          acc[m + 4][n + 2] = MFMA16(Af[m][k], Bf1[n][k], acc[m + 4][n + 2]); \
    __builtin_amdgcn_s_setprio(0);                                            \
    if (ISSC) {                                                               \
      _Pragma("unroll") for (int c = 2; c < 4; ++c) {                         \
        u32x4 wv;                                                             \
        wv.x = cvtpk(bn[2 * c].x, bn[2 * c].y);                               \
        wv.y = cvtpk(bn[2 * c].z, bn[2 * c].w);                               \
        wv.z = cvtpk(bn[2 * c + 1].x, bn[2 * c + 1].y);                       \
        wv.w = cvtpk(bn[2 * c + 1].z, bn[2 * c + 1].w);                       \
        *(u32x4*)(dbnext + c * 4096 + (tid << 3)) = wv;                       \
        if (ISSB) {                                                           \
          bn[2 * c]     = *(const f32x4*)(BGf + bro[c] + (KNXB) + swsrc);     \
          bn[2 * c + 1] = *(const f32x4*)(BGf + bro[c] + (KNXB) + swsrc + 4); \
        }                                                                     \
      }                                                                       \
    }                                                                         \
    SCHED0(); WEND; SBAR();                                                   \
  } while (0)

// ================= GEMM1: wg = x_bf @ W1_bf^T + b1 (deep-prefetch) =================
__global__ __launch_bounds__(512, 2) void k_gemm1_8ph(const u16* __restrict__ AG,
                                                      const u16* __restrict__ BG,
                                                      const float* __restrict__ bias,
                                                      u16* __restrict__ C,
                                                      float* __restrict__ wgn2) {
    __shared__ __align__(16) u16 LsA[2][16384];
    __shared__ __align__(16) u16 LsB[2][16384];
    const int K = 1024, NT = 16;
    const int lin = blockIdx.x;
    const int w = (lin & 7) * 32 + (lin >> 3);
    const int n0 = (w & 3) * 256;
    const int m0 = (w >> 2) * 256;

    const int tid = threadIdx.x, wave = tid >> 6, lane = tid & 63;
    const int lr = lane & 15, kq = lane >> 4;
    const int wr = wave >> 2, wc = wave & 3;

    const int trow = tid >> 3;
    const u32 swsrc = (u32)(((tid & 7) ^ (trow & 7)) * 8);
    const u32 saO00 = (u32)(m0 + 0 + trow) * (u32)K + swsrc;
    const u32 saO01 = (u32)(m0 + 128 + trow) * (u32)K + swsrc;
    const u32 saO10 = (u32)(m0 + 64 + trow) * (u32)K + swsrc;
    const u32 saO11 = (u32)(m0 + 192 + trow) * (u32)K + swsrc;
    const int q0 = trow, q1 = 64 + trow;
    const u32 sbO00 = (u32)(n0 + (q0 >> 5) * 64 + (q0 & 31)) * (u32)K + swsrc;
    const u32 sbO01 = (u32)(n0 + (q1 >> 5) * 64 + (q1 & 31)) * (u32)K + swsrc;
    const u32 sbO10 = (u32)(n0 + (q0 >> 5) * 64 + 32 + (q0 & 31)) * (u32)K + swsrc;
    const u32 sbO11 = (u32)(n0 + (q1 >> 5) * 64 + 32 + (q1 & 31)) * (u32)K + swsrc;
    const u32 ldst = (u32)wave * 512;

    int rpA[8], rpB[4];
#pragma unroll
    for (int mf = 0; mf < 8; ++mf)
        rpA[mf] = ((mf >> 2) * 128 + wr * 64 + (mf & 3) * 16 + lr) << 6;
#pragma unroll
    for (int nf = 0; nf < 4; ++nf)
        rpB[nf] = ((nf >> 1) * 128 + wc * 32 + (nf & 1) * 16 + lr) << 6;
    const int sw0 = ((0 + kq) ^ (lr & 7)) * 8;
    const int sw1 = ((4 + kq) ^ (lr & 7)) * 8;

    f32x4 acc[8][4] = {};

    GEMM1_PROLOGUE();

    int cur = 0;
    for (int T = 0; T < NT - 2; ++T) {
        const u16* la = &LsA[cur][0];
        const u16* lb = &LsB[cur][0];
        u16* danext = &LsA[cur ^ 1][0];
        u16* dbnext = &LsB[cur ^ 1][0];
        u16* lbw = &LsB[cur][0];
        const u32 knxa = (u32)(T + 1) * 64;
        const u32 knxb = (u32)(T + 2) * 64;
        DO_T1(1, 1, 1, 1, VMW6, VMW6, VMW6, VMW6);
        cur ^= 1;
    }
    {
        const u16* la = &LsA[cur][0];
        const u16* lb = &LsB[cur][0];
        u16* danext = &LsA[cur ^ 1][0];
        u16* dbnext = &LsB[cur ^ 1][0];
        u16* lbw = &LsB[cur][0];
        const u32 knxa = (u32)(NT - 1) * 64, knxb = 0;
        (void)knxb;
        DO_T1(1, 1, 1, 0, VMW6, VMW6, VMW6, VMW4);
        cur ^= 1;
    }
    {
        const u16* la = &LsA[cur][0];
        const u16* lb = &LsB[cur][0];
        u16* danext = &LsA[cur ^ 1][0];
        u16* dbnext = &LsB[cur ^ 1][0];
        u16* lbw = &LsB[cur][0];
        const u32 knxa = 0, knxb = 0;
        (void)danext; (void)dbnext; (void)lbw; (void)knxa; (void)knxb;
        DO_T1(0, 0, 0, 0, VMW2, VMW0, VMNOP, VMNOP);
    }

    const int col0 = n0 + wc * 64;
    const int row0 = m0 + wr * 128;
    float bcol[4];
#pragma unroll
    for (int nf = 0; nf < 4; ++nf) bcol[nf] = bias[col0 + nf * 16 + lr];
#pragma unroll
    for (int mf = 0; mf < 8; ++mf) {
#pragma unroll
        for (int r = 0; r < 4; ++r) {
            const int row = row0 + mf * 16 + kq * 4 + r;
            float nrm = 0.f;
#pragma unroll
            for (int nf = 0; nf < 4; ++nf) {
                float v = acc[mf][nf][r] + bcol[nf];
                C[(size_t)row * 1024 + col0 + nf * 16 + lr] = f2bf(v);
                nrm += v * v;
            }
#pragma unroll
            for (int off = 1; off < 16; off <<= 1) nrm += __shfl_xor(nrm, off, 64);
            if (lr == 0) atomicAdd(&wgn2[row], nrm);
        }
    }
}

// ================= GEMM2: part[z] = attn_bf @ W_mlp^T (wave-slip, fused cvt) ====
__global__ __launch_bounds__(512, 2) void k_gemm2_8ph(const u16* __restrict__ AG,
                                                      const float* __restrict__ BGf,
                                                      u16* __restrict__ part) {
    __shared__ __align__(16) u16 LsA[2][16384];
    __shared__ __align__(16) u16 LsB[2][16384];
    const int K = 16384, NT = 64;
    const int lin = blockIdx.x;
    const int w = (lin & 7) * 32 + (lin >> 3);
    const int m0 = (w & 3) * 256;
    const int z = (w >> 2) & 3;
    const int n0 = (w >> 4) * 256;
    const int kbeg = z * 4096;

    const int tid = threadIdx.x, wave = tid >> 6, lane = tid & 63;
    const int lr = lane & 15, kq = lane >> 4;
    const int wr = wave >> 2, wc = wave & 3;

    const int trow = tid >> 3;
    const u32 swsrc = (u32)(((tid & 7) ^ (trow & 7)) * 8);
    const u32 saO00 = (u32)(m0 + 0 + trow) * (u32)K + (u32)kbeg + swsrc;
    const u32 saO01 = (u32)(m0 + 128 + trow) * (u32)K + (u32)kbeg + swsrc;
    const u32 saO10 = (u32)(m0 + 64 + trow) * (u32)K + (u32)kbeg + swsrc;
    const u32 saO11 = (u32)(m0 + 192 + trow) * (u32)K + (u32)kbeg + swsrc;
    const int q0 = trow, q1 = 64 + trow;
    u32 bro[4];
    bro[0] = (u32)(n0 + (q0 >> 5) * 64 + (q0 & 31)) * 16384u + (u32)kbeg;
    bro[1] = (u32)(n0 + (q1 >> 5) * 64 + (q1 & 31)) * 16384u + (u32)kbeg;
    bro[2] = bro[0] + 32u * 16384u;
    bro[3] = bro[1] + 32u * 16384u;
    const u32 ldst = (u32)wave * 512;

    int rpA[8], rpB[4];
#pragma unroll
    for (int mf = 0; mf < 8; ++mf)
        rpA[mf] = ((mf >> 2) * 128 + wr * 64 + (mf & 3) * 16 + lr) << 6;
#pragma unroll
    for (int nf = 0; nf < 4; ++nf)
        rpB[nf] = ((nf >> 1) * 128 + wc * 32 + (nf & 1) * 16 + lr) << 6;
    const int sw0 = ((0 + kq) ^ (lr & 7)) * 8;
    const int sw1 = ((4 + kq) ^ (lr & 7)) * 8;

    f32x4 acc[8][4] = {};
    f32x4 bn[8];

    // prologue: tile0 (A gll16, bn f32 load + cvt -> LsB[0]); preload bn(T1)
    {
        gll16(AG + saO00, &LsA[0][0] + ldst);
        gll16(AG + saO01, &LsA[0][0] + 4096 + ldst);
        gll16(AG + saO10, &LsA[0][0] + 8192 + ldst);
        gll16(AG + saO11, &LsA[0][0] + 8192 + 4096 + ldst);
#pragma unroll
        for (int c = 0; c < 4; ++c) {
            bn[2 * c]     = *(const f32x4*)(BGf + bro[c] + swsrc);
            bn[2 * c + 1] = *(const f32x4*)(BGf + bro[c] + swsrc + 4);
        }
#pragma unroll
        for (int c = 0; c < 4; ++c) {
            u32x4 wv;
            wv.x = cvtpk(bn[2 * c].x, bn[2 * c].y);
            wv.y = cvtpk(bn[2 * c].z, bn[2 * c].w);
            wv.z = cvtpk(bn[2 * c + 1].x, bn[2 * c + 1].y);
            wv.w = cvtpk(bn[2 * c + 1].z, bn[2 * c + 1].w);
            *(u32x4*)(&LsB[0][0] + c * 4096 + (tid << 3)) = wv;
        }
        asm volatile("s_waitcnt vmcnt(0) lgkmcnt(0)" ::: "memory");
#pragma unroll
        for (int c = 0; c < 4; ++c) {
            bn[2 * c]     = *(const f32x4*)(BGf + bro[c] + 64 + swsrc);
            bn[2 * c + 1] = *(const f32x4*)(BGf + bro[c] + 64 + swsrc + 4);
        }
        SBAR();
    }

    int cur = 0;
    for (int T = 0; T < NT - 2; ++T) {
        const u16* la = &LsA[cur][0];
        const u16* lb = &LsB[cur][0];
        u16* danext = &LsA[cur ^ 1][0];
        u16* dbnext = &LsB[cur ^ 1][0];
        const u32 knxa = (u32)(T + 1) * 64;
        const u32 knxb = (u32)(T + 2) * 64;
        GT3(1, 1, 1, knxa, knxb, VMW8L);
        cur ^= 1;
    }
    {   // T = 62
        const u16* la = &LsA[cur][0];
        const u16* lb = &LsB[cur][0];
        u16* danext = &LsA[cur ^ 1][0];
        u16* dbnext = &LsB[cur ^ 1][0];
        GT3(1, 1, 0, 63u * 64, 0u, VMW0L);
        cur ^= 1;
    }
    {   // T = 63
        const u16* la = &LsA[cur][0];
        const u16* lb = &LsB[cur][0];
        u16* danext = &LsA[cur ^ 1][0];
        u16* dbnext = &LsB[cur ^ 1][0];
        (void)danext; (void)dbnext;
        GT3(0, 0, 0, 0u, 0u, VMNOP);
    }

    u16* po = part + (size_t)z * 4194304ull;
    const int col0 = n0 + wc * 64;
    const int row0 = m0 + wr * 128;
#pragma unroll
    for (int mf = 0; mf < 8; ++mf)
#pragma unroll
        for (int r = 0; r < 4; ++r) {
            const int row = row0 + mf * 16 + kq * 4 + r;
#pragma unroll
            for (int nf = 0; nf < 4; ++nf)
                po[(size_t)row * 4096 + col0 + nf * 16 + lr] = f2bf(acc[mf][nf][r]);
        }
}

// ---------- merged per-batch graph algebra + attention readout ----------
__global__ __launch_bounds__(256) void k_batch_attn(const u16* xb,
                                                    const u16* __restrict__ wgb,
                                                    const float* __restrict__ xinv,
                                                    const float* __restrict__ wgn2,
                                                    const float* __restrict__ matrix,
                                                    const float* __restrict__ a_param,
                                                    float* __restrict__ e2_out,
                                                    float* __restrict__ m_out,
                                                    u16* attn_bf) {
    const int b = blockIdx.x, tid = threadIdx.x;
    const int wave = tid >> 6, lane = tid & 63;
    const int j = lane & 15, ig = (lane >> 4) * 4;

    __shared__ float qred[4][64][4];
    __shared__ float esm_l[16 * 17];
    __shared__ float fi_l[16 * 17];
    __shared__ float e2_l[16 * 17];
    __shared__ float m_l[256];
    __shared__ float as_l[256];
    __shared__ u16 xsh[16][256];

    {
        const size_t roff = (size_t)(b * 16 + j) * 1024 + (lane >> 4) * 8 + wave * 256;
        f32x4 acc0 = {}, acc1 = {};
#pragma unroll
        for (int kt = 0; kt < 256; kt += 64) {
            short8 xa0 = *(const short8*)(xb + roff + kt);
            short8 wa0 = *(const short8*)(wgb + roff + kt);
            short8 xa1 = *(const short8*)(xb + roff + kt + 32);
            short8 wa1 = *(const short8*)(wgb + roff + kt + 32);
            acc0 = __builtin_amdgcn_mfma_f32_16x16x32_bf16(xa0, wa0, acc0, 0, 0, 0);
            acc1 = __builtin_amdgcn_mfma_f32_16x16x32_bf16(xa1, wa1, acc1, 0, 0, 0);
        }
#pragma unroll
        for (int r = 0; r < 4; ++r) qred[wave][lane][r] = acc0[r] + acc1[r];
    }
    __syncthreads();

    if (tid < 64) {
        const int l = tid;
        const float inw = 1.0f / fmaxf(sqrtf(wgn2[b * 16 + j]), 1e-12f);
        const float boost = 1.0f + a_param[0];
        float e[4];
#pragma unroll
        for (int r = 0; r < 4; ++r) {
            const int i = ig + r;
            float v = (qred[0][l][r] + qred[1][l][r] + qred[2][l][r] + qred[3][l][r]) *
                      xinv[b * 16 + i] * inw;
            if (i == j) v *= boost;
            e[r] = v;
            as_l[i * 16 + j] = v;
        }
        float mx = fmaxf(fmaxf(e[0], e[1]), fmaxf(e[2], e[3]));
        mx = fmaxf(mx, __shfl_xor(mx, 16, 64));
        mx = fmaxf(mx, __shfl_xor(mx, 32, 64));
        float p[4], s = 0.f;
#pragma unroll
        for (int r = 0; r < 4; ++r) { p[r] = __expf(e[r] - mx); s += p[r]; }
        s += __shfl_xor(s, 16, 64);
        s += __shfl_xor(s, 32, 64);
        const float invs = 1.0f / s;
#pragma unroll
        for (int r = 0; r < 4; ++r) esm_l[(ig + r) * 17 + j] = p[r] * invs;
        const f32x4 mv = *(const f32x4*)(matrix + (size_t)b * 256 + 4 * l);
        *(f32x4*)(m_l + 4 * l) = mv;
        *(f32x4*)(m_out + (size_t)b * 256 + 4 * l) = mv;
    }
    __syncthreads();
    if (tid < 64) {
        float fi[4] = {0, 0, 0, 0};
#pragma unroll
        for (int t = 0; t < 16; ++t) {
            const float mk = m_l[t * 16 + j];
#pragma unroll
            for (int r = 0; r < 4; ++r) fi[r] += esm_l[(ig + r) * 17 + t] * mk;
        }
#pragma unroll
        for (int r = 0; r < 4; ++r) fi_l[(ig + r) * 17 + j] = fi[r];
    }
    __syncthreads();
    if (tid < 64) {
        float e2v[4] = {0, 0, 0, 0};
#pragma unroll
        for (int kk = 0; kk < 16; ++kk) {
            const float wgt = esm_l[j * 17 + kk] * m_l[kk * 16 + kk];
#pragma unroll
            for (int r = 0; r < 4; ++r) e2v[r] += fi_l[(ig + r) * 17 + kk] * wgt;
        }
#pragma unroll
        for (int r = 0; r < 4; ++r) e2_l[(ig + r) * 17 + j] = e2v[r];
    }
    __syncthreads();
    if (tid < 64) {
#pragma unroll
        for (int r = 0; r < 4; ++r) {
            const int i = ig + r;
            e2_out[(size_t)b * 256 + i * 16 + j] =
                0.5f * (e2_l[i * 17 + j] + e2_l[j * 17 + i]);
        }
    }

    const int srow = tid >> 4;
    const int scol = (tid & 15) * 16;
    for (int ch = 0; ch < 4; ++ch) {
        __syncthreads();
        const u16* src = xb + ((size_t)b * 16 + srow) * 1024 + ch * 256 + scol;
        *(short8*)&xsh[srow][scol] = *(const short8*)src;
        *(short8*)&xsh[srow][scol + 8] = *(const short8*)(src + 8);
        __syncthreads();
        float accv[16] = {};
#pragma unroll
        for (int jj = 0; jj < 16; ++jj) {
            const float xv = bf2f(xsh[jj][tid]);
#pragma unroll
            for (int i = 0; i < 16; ++i) accv[i] = fmaf(as_l[jj * 16 + i], xv, accv[i]);
        }
#pragma unroll
        for (int i = 0; i < 16; ++i)
            attn_bf[((size_t)b * 16 + i) * 1024 + ch * 256 + tid] = f2bf(ftanh(accv[i]));
    }
}

// ---------- broadcast: out[b, rep, :] = sum_z part[z][b,:] + b_mlp ----------
__global__ __launch_bounds__(256) void k_bcast(const u16* __restrict__ p,
                                               const float* __restrict__ bias,
                                               float* __restrict__ out) {
    const size_t i = (size_t)blockIdx.x * 256 + threadIdx.x;
    const int o4 = (int)(i & 1023);
    const int b = (int)(i >> 14);
    const size_t src = (size_t)b * 4096 + (size_t)o4 * 4;
    f32x4 r = *(const f32x4*)(bias + (size_t)o4 * 4);
#pragma unroll
    for (int z = 0; z < 4; ++z) {
        us4 v = *(const us4*)(p + (size_t)z * 4194304ull + src);
        r.x += bf2f(v.x); r.y += bf2f(v.y); r.z += bf2f(v.z); r.w += bf2f(v.w);
    }
    *(f32x4*)(out + i * 4) = r;
}

extern "C" void kernel_launch(void* const* d_in, const int* in_sizes, int n_in,
                              void* d_out, int out_size, void* d_ws, size_t ws_size,
                              hipStream_t stream) {
    const float* x      = (const float*)d_in[0];
    const float* matrix = (const float*)d_in[1];
    const float* W1     = (const float*)d_in[2];
    const float* b1     = (const float*)d_in[3];
    const float* W_mlp  = (const float*)d_in[4];
    const float* b_mlp  = (const float*)d_in[5];
    const float* a_par  = (const float*)d_in[6];
    float* out = (float*)d_out;

    char* ws = (char*)d_ws;
    size_t off = 0;
    auto alloc = [&](size_t bytes) {
        char* p = ws + off;
        off += (bytes + 255) & ~(size_t)255;
        return p;
    };
    u16*   x_bf  = (u16*)alloc(16384ull * 1024 * 2);    // reused as attn_bf
    u16*   wg_bf = (u16*)alloc(16384ull * 1024 * 2);    // reused as GEMM2 bf16 partials
    u16*   w1_bf = (u16*)alloc(1024ull * 1024 * 2);
    float* xinv  = (float*)alloc(16384ull * 4);
    float* wgn2  = (float*)alloc(16384ull * 4);
    u16*   attn_bf = x_bf;
    u16*   part    = wg_bf;
    float* e2_out = out + 67108864ull;
    float* m_out  = out + 67371008ull;

    hipMemsetAsync(wgn2, 0, 16384 * 4, stream);
    k_cvt_x<<<17408, 256, 0, stream>>>(x, x_bf, xinv, W1, w1_bf);
    k_gemm1_8ph<<<256, 512, 0, stream>>>(x_bf, w1_bf, b1, wg_bf, wgn2);
    k_batch_attn<<<1024, 256, 0, stream>>>(x_bf, wg_bf, xinv, wgn2, matrix, a_par,
                                           e2_out, m_out, attn_bf);
    k_gemm2_8ph<<<256, 512, 0, stream>>>(attn_bf, W_mlp, part);
    k_bcast<<<65536, 256, 0, stream>>>(part, b_mlp, out);
}